// Round 13
// baseline (124.741 us; speedup 1.0000x reference)
//
#include <hip/hip_runtime.h>

#define NB 64
#define NN 4096
#define NC 128
#define NH 4
#define HC (NH * NC)        // 512
#define NHW 32              // half-waves per block (1024 threads)
#define LRELU 0.2f

// ONE kernel does everything for its graph b: wt/bt from W&tune, V-stream with
// online (no-max) softmax accumulation, in-LDS merge, output GEMV. 64 blocks,
// zero cross-block communication -> single graph node.
__global__ __launch_bounds__(1024, 4) void mega(const float* __restrict__ V,
                                                const int* __restrict__ gs,
                                                const float* __restrict__ W,
                                                const float* __restrict__ bias,
                                                const float* __restrict__ tune,
                                                float* __restrict__ out)
{
    const int b = blockIdx.x;
    const int tid = threadIdx.x;

    __shared__ float tuneS[HC];              // tune[h][c]
    __shared__ float wtL[NC * NH];           // wt[k*4+h]
    __shared__ float btL[NH];
    __shared__ float llds[NHW][NH];
    __shared__ float Sall[NHW][NH][NC + 4];  // padded, 67.5 KB
    __shared__ float LhS[NH];
    __shared__ float SnS[NH][NC];
    __shared__ float gemv[2][HC];

    // ---------- phase 1: wt[k][h] = sum_c W[k, h*C+c]*tune[h,c]; bt[h] = sum_c bias*tune
    if (tid < HC / 4)
        reinterpret_cast<float4*>(tuneS)[tid] = reinterpret_cast<const float4*>(tune)[tid];
    __syncthreads();
    if (tid < 512) {
        const int k = tid >> 2, h = tid & 3;
        const float* wrow = W + (size_t)k * HC + h * NC;
        const float* trow = tuneS + h * NC;
        float acc = 0.f;
        #pragma unroll 8
        for (int u = 0; u < NC / 4; ++u) {
            const float4 wv = reinterpret_cast<const float4*>(wrow)[u];
            const float4 tv = reinterpret_cast<const float4*>(trow)[u];
            acc += wv.x * tv.x + wv.y * tv.y + wv.z * tv.z + wv.w * tv.w;
        }
        wtL[k * NH + h] = acc;
    } else if (tid < 512 + 128) {
        const int t2 = tid - 512;
        const int h = t2 >> 5, l5 = t2 & 31;
        const float4 bv = reinterpret_cast<const float4*>(bias + h * NC)[l5];
        const float4 tv = reinterpret_cast<const float4*>(tuneS + h * NC)[l5];
        float p = bv.x * tv.x + bv.y * tv.y + bv.z * tv.z + bv.w * tv.w;
        #pragma unroll
        for (int off = 16; off; off >>= 1) p += __shfl_xor(p, off, 32);
        if (l5 == 0) btL[h] = p;
    }
    __syncthreads();

    // ---------- phase 2: stream V rows. Half-wave s owns contiguous segment
    // [s*seg, min((s+1)*seg, gs)), seg = ceil(gs/32). Lane = h*8+j owns features
    // [16j,16j+16) of head h; logit reduce = 3-shuffle butterfly; no max tracking
    // (logits ~ N(0,~1), exp safe in fp32); 2-deep clamped prefetch.
    const int gsz = gs[b];
    const int s = tid >> 5;           // 0..31
    const int lane = tid & 31;
    const int h = lane >> 3;
    const int j = lane & 7;

    float wtk[16];
    #pragma unroll
    for (int u = 0; u < 16; ++u) wtk[u] = wtL[(16 * j + u) * NH + h];
    const float bt = btL[h];

    const int seg = (gsz + NHW - 1) >> 5;
    const int beg = s * seg;
    int iters = gsz - beg;
    iters = (iters < 0) ? 0 : (iters > seg ? seg : iters);

    float l = 0.f;
    float S[16] = {};

    const float* vp = V + ((size_t)b * NN + beg) * NC + j * 16;

    float4 A0, A1, A2, A3, B0, B1, B2, B3;
    if (iters > 0) {
        A0 = reinterpret_cast<const float4*>(vp)[0];
        A1 = reinterpret_cast<const float4*>(vp)[1];
        A2 = reinterpret_cast<const float4*>(vp)[2];
        A3 = reinterpret_cast<const float4*>(vp)[3];
        const float* p1 = vp + (iters > 1 ? NC : 0);
        B0 = reinterpret_cast<const float4*>(p1)[0];
        B1 = reinterpret_cast<const float4*>(p1)[1];
        B2 = reinterpret_cast<const float4*>(p1)[2];
        B3 = reinterpret_cast<const float4*>(p1)[3];
    }
    for (int i = 0; i < iters; ++i) {
        const float* p2 = vp + (i + 2 < iters ? 2 * NC : 0);   // clamped prefetch
        const float4 C0 = reinterpret_cast<const float4*>(p2)[0];
        const float4 C1 = reinterpret_cast<const float4*>(p2)[1];
        const float4 C2 = reinterpret_cast<const float4*>(p2)[2];
        const float4 C3 = reinterpret_cast<const float4*>(p2)[3];
        vp += NC;

        float a0 = A0.x * wtk[0]  + A0.y * wtk[1]  + A0.z * wtk[2]  + A0.w * wtk[3];
        float a1 = A1.x * wtk[4]  + A1.y * wtk[5]  + A1.z * wtk[6]  + A1.w * wtk[7];
        float a2 = A2.x * wtk[8]  + A2.y * wtk[9]  + A2.z * wtk[10] + A2.w * wtk[11];
        float a3 = A3.x * wtk[12] + A3.y * wtk[13] + A3.z * wtk[14] + A3.w * wtk[15];
        float lg = (a0 + a1) + (a2 + a3);
        lg += __shfl_xor(lg, 1, 32);
        lg += __shfl_xor(lg, 2, 32);
        lg += __shfl_xor(lg, 4, 32);   // 8-lane head group holds full logit
        float x = lg + bt;
        x = (x >= 0.f) ? x : LRELU * x;               // leaky_relu
        const float p = __expf(x);                    // no max subtraction
        l += p;
        S[0]  += p * A0.x;  S[1]  += p * A0.y;  S[2]  += p * A0.z;  S[3]  += p * A0.w;
        S[4]  += p * A1.x;  S[5]  += p * A1.y;  S[6]  += p * A1.z;  S[7]  += p * A1.w;
        S[8]  += p * A2.x;  S[9]  += p * A2.y;  S[10] += p * A2.z;  S[11] += p * A2.w;
        S[12] += p * A3.x;  S[13] += p * A3.y;  S[14] += p * A3.z;  S[15] += p * A3.w;
        A0 = B0; A1 = B1; A2 = B2; A3 = B3;
        B0 = C0; B1 = C1; B2 = C2; B3 = C3;
    }

    // ---------- phase 3: in-LDS merge across 32 half-waves, then output GEMV
    if (j == 0) llds[s][h] = l;
    #pragma unroll
    for (int t = 0; t < 4; ++t) {
        float4 s4;
        s4.x = S[4 * t]; s4.y = S[4 * t + 1]; s4.z = S[4 * t + 2]; s4.w = S[4 * t + 3];
        *reinterpret_cast<float4*>(&Sall[s][h][16 * j + 4 * t]) = s4;
    }
    __syncthreads();
    if (tid < NH) {
        float L = 0.f;
        #pragma unroll
        for (int ss = 0; ss < NHW; ++ss) L += llds[ss][tid];
        LhS[tid] = L;
    }
    __syncthreads();
    if (tid < 512) {
        const int hh = tid >> 7, k = tid & 127;
        float ssum = 0.f;
        #pragma unroll
        for (int ss = 0; ss < NHW; ++ss) ssum += Sall[ss][hh][k];
        SnS[hh][k] = ssum / LhS[hh];
    }
    __syncthreads();
    {
        const int d = tid & 511;
        const int halfk = tid >> 9;           // 0 or 1: k-range split
        const int hh = d >> 7;
        const float* wcol = W + (size_t)(halfk * 64) * HC + d;
        const float* snp = &SnS[hh][halfk * 64];
        float acc = 0.f;
        #pragma unroll 8
        for (int k = 0; k < 64; ++k) acc += snp[k] * wcol[(size_t)k * HC];
        gemv[halfk][d] = acc;
    }
    __syncthreads();
    if (tid < 512)
        out[(size_t)b * HC + tid] = gemv[0][tid] + gemv[1][tid] + bias[tid];
}

extern "C" void kernel_launch(void* const* d_in, const int* in_sizes, int n_in,
                              void* d_out, int out_size, void* d_ws, size_t ws_size,
                              hipStream_t stream)
{
    const float* V    = (const float*)d_in[0];
    const int*   gsz  = (const int*)d_in[1];
    const float* W    = (const float*)d_in[2];
    const float* bias = (const float*)d_in[3];
    const float* tune = (const float*)d_in[4];
    float* out = (float*)d_out;

    hipLaunchKernelGGL(mega, dim3(NB), dim3(1024), 0, stream, V, gsz, W, bias, tune, out);
}

// Round 14
// 73.824 us; speedup vs baseline: 1.6897x; 1.6897x over previous
//
#include <hip/hip_runtime.h>

#define NB 64
#define NN 4096
#define NC 128
#define NH 4
#define HC (NH * NC)        // 512
#define PSTRIDE (8 + HC)    // 520 floats per partial: [4 pad][4 L][512 S]
#define NSLICE 32           // 32*64 = 2048 blocks -> 8192 waves -> 8 waves/SIMD
#define LRELU 0.2f

// ---------------- k0: wt[k][h] = sum_c W[k, h*C+c] * t[h,c];  bt[h] = sum_c bias*t.
__global__ __launch_bounds__(128) void k0_wt(const float* __restrict__ W,
                                             const float* __restrict__ bias,
                                             const float* __restrict__ tune,
                                             float* __restrict__ wtbt)
{
    const int bid = blockIdx.x;
    const int t = threadIdx.x;                       // 0..127
    const float* src = (bid < NC) ? (W + (size_t)bid * HC) : bias;
    float* dst = (bid < NC) ? (wtbt + bid * NH) : (wtbt + NC * NH);
    const float4 a = reinterpret_cast<const float4*>(src)[t];
    const float4 b = reinterpret_cast<const float4*>(tune)[t];
    float p = a.x * b.x + a.y * b.y + a.z * b.z + a.w * b.w;
    #pragma unroll
    for (int off = 16; off; off >>= 1) p += __shfl_xor(p, off, 32);
    if ((t & 31) == 0) dst[t >> 5] = p;              // group t>>5 == head h
}

// ---------------- k1: grid (NSLICE, NB). BALANCED CONTIGUOUS SEGMENTS:
// half-wave w = slice*8+hw owns rows [w*seg, min((w+1)*seg, gs)), seg = ceil(gs/256).
// Identical loop to r12; the ONLY change this round is NSLICE 16->32 (+launch_bounds 8):
// 2048 blocks -> 8 resident waves/SIMD so latency stalls can be hidden by TLP.
__global__ __launch_bounds__(256, 8) void k1_part(const float* __restrict__ V,
                                                  const int* __restrict__ gs,
                                                  const float* __restrict__ wtbt,
                                                  float* __restrict__ part)
{
    const int slice = blockIdx.x;
    const int b = blockIdx.y;
    const int tid = threadIdx.x;
    const int hw = tid >> 5;          // half-wave 0..7
    const int lane = tid & 31;
    const int h = lane >> 3;          // head 0..3
    const int j = lane & 7;           // feature-group (features 16j..16j+15)
    const int w = slice * 8 + hw;     // global half-wave index in [0,256)
    const int gsz = gs[b];

    float wtk[16];
    #pragma unroll
    for (int u = 0; u < 16; ++u) wtk[u] = wtbt[(16 * j + u) * NH + h];
    const float bt = wtbt[HC + h];

    const int seg = (gsz + 255) >> 8;            // rows per half-wave
    const int beg = w * seg;
    int iters = gsz - beg;
    iters = (iters < 0) ? 0 : (iters > seg ? seg : iters);

    float l = 0.f;
    float S[16] = {};

    const float* vp = V + ((size_t)b * NN + beg) * NC + j * 16;   // next row = +NC floats

    float4 A0, A1, A2, A3, B0, B1, B2, B3;
    if (iters > 0) {
        A0 = reinterpret_cast<const float4*>(vp)[0];
        A1 = reinterpret_cast<const float4*>(vp)[1];
        A2 = reinterpret_cast<const float4*>(vp)[2];
        A3 = reinterpret_cast<const float4*>(vp)[3];
        const float* p1 = vp + (iters > 1 ? NC : 0);
        B0 = reinterpret_cast<const float4*>(p1)[0];
        B1 = reinterpret_cast<const float4*>(p1)[1];
        B2 = reinterpret_cast<const float4*>(p1)[2];
        B3 = reinterpret_cast<const float4*>(p1)[3];
    }
    for (int i = 0; i < iters; ++i) {
        const float* p2 = vp + (i + 2 < iters ? 2 * NC : 0);   // clamped prefetch
        const float4 C0 = reinterpret_cast<const float4*>(p2)[0];
        const float4 C1 = reinterpret_cast<const float4*>(p2)[1];
        const float4 C2 = reinterpret_cast<const float4*>(p2)[2];
        const float4 C3 = reinterpret_cast<const float4*>(p2)[3];
        vp += NC;

        float a0 = A0.x * wtk[0]  + A0.y * wtk[1]  + A0.z * wtk[2]  + A0.w * wtk[3];
        float a1 = A1.x * wtk[4]  + A1.y * wtk[5]  + A1.z * wtk[6]  + A1.w * wtk[7];
        float a2 = A2.x * wtk[8]  + A2.y * wtk[9]  + A2.z * wtk[10] + A2.w * wtk[11];
        float a3 = A3.x * wtk[12] + A3.y * wtk[13] + A3.z * wtk[14] + A3.w * wtk[15];
        float lg = (a0 + a1) + (a2 + a3);
        lg += __shfl_xor(lg, 1, 32);
        lg += __shfl_xor(lg, 2, 32);
        lg += __shfl_xor(lg, 4, 32);   // 8-lane head group holds full logit
        float x = lg + bt;
        x = (x >= 0.f) ? x : LRELU * x;               // leaky_relu
        const float p = __expf(x);                    // no max subtraction
        l += p;
        S[0]  += p * A0.x;  S[1]  += p * A0.y;  S[2]  += p * A0.z;  S[3]  += p * A0.w;
        S[4]  += p * A1.x;  S[5]  += p * A1.y;  S[6]  += p * A1.z;  S[7]  += p * A1.w;
        S[8]  += p * A2.x;  S[9]  += p * A2.y;  S[10] += p * A2.z;  S[11] += p * A2.w;
        S[12] += p * A3.x;  S[13] += p * A3.y;  S[14] += p * A3.z;  S[15] += p * A3.w;
        A0 = B0; A1 = B1; A2 = B2; A3 = B3;
        B0 = C0; B1 = C1; B2 = C2; B3 = C3;
    }

    // ---- block combine across 8 half-waves
    __shared__ float llds[8][4];
    __shared__ float Sall[8][4][132];    // padded
    if (j == 0) llds[hw][h] = l;
    #pragma unroll
    for (int t = 0; t < 4; ++t) {
        float4 s4;
        s4.x = S[4 * t]; s4.y = S[4 * t + 1]; s4.z = S[4 * t + 2]; s4.w = S[4 * t + 3];
        *reinterpret_cast<float4*>(&Sall[hw][h][16 * j + 4 * t]) = s4;
    }
    __syncthreads();
    float* pb = part + (size_t)(b * NSLICE + slice) * PSTRIDE;
    if (tid < 4) {
        float L = 0.f;
        #pragma unroll
        for (int ww = 0; ww < 8; ++ww) L += llds[ww][tid];
        pb[4 + tid] = L;
    }
    #pragma unroll
    for (int r = 0; r < 2; ++r) {
        const int e = tid + r * 256;
        const int hh = e >> 7, k = e & 127;
        float s = 0.f;
        #pragma unroll
        for (int ww = 0; ww < 8; ++ww) s += Sall[ww][hh][k];
        pb[8 + e] = s;
    }
}

// ---------------- k2: block (b, h): merge NSLICE partials for head h, then
// out[b, h*128+d] = (S[h]/L[h]) . W[:, h*128+d] + bias[h*128+d]
__global__ __launch_bounds__(128) void k2_out(const float* __restrict__ part,
                                              const float* __restrict__ W,
                                              const float* __restrict__ bias,
                                              float* __restrict__ out)
{
    const int b = blockIdx.x;
    const int h = blockIdx.y;
    const int tid = threadIdx.x;     // 0..127
    const float* pb = part + (size_t)b * NSLICE * PSTRIDE;

    __shared__ float Sn[NC];
    __shared__ float sL;
    if (tid == 0) {
        float L = 0.f;
        #pragma unroll
        for (int c = 0; c < NSLICE; ++c) L += pb[(size_t)c * PSTRIDE + 4 + h];
        sL = L;
    }
    __syncthreads();
    {
        float s = 0.f;
        #pragma unroll 8
        for (int c = 0; c < NSLICE; ++c)
            s += pb[(size_t)c * PSTRIDE + 8 + h * NC + tid];
        Sn[tid] = s / sL;
    }
    __syncthreads();
    const int d = h * NC + tid;
    float acc = 0.f;
    #pragma unroll 4
    for (int k = 0; k < NC; ++k) acc += Sn[k] * W[(size_t)k * HC + d];
    out[(size_t)b * HC + d] = acc + bias[d];
}

extern "C" void kernel_launch(void* const* d_in, const int* in_sizes, int n_in,
                              void* d_out, int out_size, void* d_ws, size_t ws_size,
                              hipStream_t stream)
{
    const float* V    = (const float*)d_in[0];
    const int*   gsz  = (const int*)d_in[1];
    const float* W    = (const float*)d_in[2];
    const float* bias = (const float*)d_in[3];
    const float* tune = (const float*)d_in[4];
    float* out  = (float*)d_out;
    float* wtbt = (float*)d_ws;            // 520 floats (516 used)
    float* part = wtbt + PSTRIDE;          // NB*NSLICE*PSTRIDE floats (~4.3 MB)

    hipLaunchKernelGGL(k0_wt, dim3(NC + 1), dim3(128), 0, stream, W, bias, tune, wtbt);
    hipLaunchKernelGGL(k1_part, dim3(NSLICE, NB), dim3(256), 0, stream, V, gsz, wtbt, part);
    hipLaunchKernelGGL(k2_out, dim3(NB, NH), dim3(128), 0, stream, part, W, bias, out);
}

// Round 15
// 44.201 us; speedup vs baseline: 2.8222x; 1.6702x over previous
//
#include <hip/hip_runtime.h>

#define NB 64
#define NN 4096
#define NC 128
#define NH 4
#define HC (NH * NC)        // 512
#define PSTRIDE (8 + HC)    // 520 floats per partial: [4 pad][4 L][512 S]
#define NSLICE 16           // 16*64 = 1024 blocks
#define TROWS 64            // rows per LDS tile (32 KB)
#define LRELU 0.2f

// ---------------- k0: wt[k][h] = sum_c W[k, h*C+c] * t[h,c];  bt[h] = sum_c bias*t.
__global__ __launch_bounds__(128) void k0_wt(const float* __restrict__ W,
                                             const float* __restrict__ bias,
                                             const float* __restrict__ tune,
                                             float* __restrict__ wtbt)
{
    const int bid = blockIdx.x;
    const int t = threadIdx.x;                       // 0..127
    const float* src = (bid < NC) ? (W + (size_t)bid * HC) : bias;
    float* dst = (bid < NC) ? (wtbt + bid * NH) : (wtbt + NC * NH);
    const float4 a = reinterpret_cast<const float4*>(src)[t];
    const float4 b = reinterpret_cast<const float4*>(tune)[t];
    float p = a.x * b.x + a.y * b.y + a.z * b.z + a.w * b.w;
    #pragma unroll
    for (int off = 16; off; off >>= 1) p += __shfl_xor(p, off, 32);
    if ((t & 31) == 0) dst[t >> 5] = p;              // group t>>5 == head h
}

// ---------------- k1: grid (NSLICE, NB). Block owns contiguous rows
// [slice*segB, min(+segB, gs)), segB = ceil(gs/16). LDS-STAGED: loop over 64-row
// tiles {stage 32KB to LDS via 8 independent float4 loads/thread -> barrier ->
// compute from LDS}. Staging loads have no register consumer -> stay in flight;
// compute reads are ds_read_b128 (~120cy, hideable). Invalid rows masked p=0.
__global__ __launch_bounds__(256, 4) void k1_part(const float* __restrict__ V,
                                                  const int* __restrict__ gs,
                                                  const float* __restrict__ wtbt,
                                                  float* __restrict__ part)
{
    __shared__ float smem[8192];                     // 32 KB, unioned
    float (*Vt)[NC] = reinterpret_cast<float(*)[NC]>(smem);          // [64][128]
    float (*Sall)[NH][132] = reinterpret_cast<float(*)[NH][132]>(smem); // [8][4][132]
    float* llds = smem + 8 * NH * 132;               // 32 floats

    const int slice = blockIdx.x;
    const int b = blockIdx.y;
    const int tid = threadIdx.x;
    const int hw = tid >> 5;          // half-wave 0..7
    const int lane = tid & 31;
    const int h = lane >> 3;          // head 0..3
    const int j = lane & 7;           // feature-group (features 16j..16j+15)
    const int gsz = gs[b];

    float wtk[16];
    #pragma unroll
    for (int u = 0; u < 16; ++u) wtk[u] = wtbt[(16 * j + u) * NH + h];
    const float bt = wtbt[HC + h];

    const int segB = (gsz + NSLICE - 1) / NSLICE;    // rows per block
    const int myBeg = slice * segB;
    int myEnd = myBeg + segB;
    if (myEnd > gsz) myEnd = gsz;
    const int nrows = (myEnd > myBeg) ? (myEnd - myBeg) : 0;
    const int ntile = (nrows + TROWS - 1) / TROWS;

    float l = 0.f;
    float S[16] = {};

    const float4* Vg4 = reinterpret_cast<const float4*>(V);
    const size_t gbase = (size_t)b * NN;

    for (int tile = 0; tile < ntile; ++tile) {
        const int tbase = myBeg + tile * TROWS;
        // ---- stage: 2048 float4; thread t does idx = t + 256k (8 independent loads)
        float4 r[8];
        #pragma unroll
        for (int k = 0; k < 8; ++k) {
            const int idx = tid + (k << 8);
            const int row = idx >> 5;                 // 0..63
            const int gr = tbase + row;
            const int src_row = (gr < myEnd) ? gr : myBeg;   // clamp (masked later)
            r[k] = Vg4[(gbase + src_row) * 32 + (idx & 31)];
        }
        #pragma unroll
        for (int k = 0; k < 8; ++k) {
            const int idx = tid + (k << 8);
            reinterpret_cast<float4*>(smem)[idx] = r[k];
        }
        __syncthreads();
        // ---- compute: half-wave hw handles rows hw*8 .. hw*8+7 from LDS
        #pragma unroll 2
        for (int rr = 0; rr < 8; ++rr) {
            const int row = (hw << 3) + rr;
            const bool valid = (tbase + row < myEnd);
            const float4* vr = reinterpret_cast<const float4*>(&Vt[row][j * 16]);
            const float4 A0 = vr[0];
            const float4 A1 = vr[1];
            const float4 A2 = vr[2];
            const float4 A3 = vr[3];
            float a0 = A0.x * wtk[0]  + A0.y * wtk[1]  + A0.z * wtk[2]  + A0.w * wtk[3];
            float a1 = A1.x * wtk[4]  + A1.y * wtk[5]  + A1.z * wtk[6]  + A1.w * wtk[7];
            float a2 = A2.x * wtk[8]  + A2.y * wtk[9]  + A2.z * wtk[10] + A2.w * wtk[11];
            float a3 = A3.x * wtk[12] + A3.y * wtk[13] + A3.z * wtk[14] + A3.w * wtk[15];
            float lg = (a0 + a1) + (a2 + a3);
            lg += __shfl_xor(lg, 1, 32);
            lg += __shfl_xor(lg, 2, 32);
            lg += __shfl_xor(lg, 4, 32);   // 8-lane head group holds full logit
            float x = lg + bt;
            x = (x >= 0.f) ? x : LRELU * x;           // leaky_relu
            float p = __expf(x);                      // no max subtraction
            p = valid ? p : 0.f;
            l += p;
            S[0]  += p * A0.x;  S[1]  += p * A0.y;  S[2]  += p * A0.z;  S[3]  += p * A0.w;
            S[4]  += p * A1.x;  S[5]  += p * A1.y;  S[6]  += p * A1.z;  S[7]  += p * A1.w;
            S[8]  += p * A2.x;  S[9]  += p * A2.y;  S[10] += p * A2.z;  S[11] += p * A2.w;
            S[12] += p * A3.x;  S[13] += p * A3.y;  S[14] += p * A3.z;  S[15] += p * A3.w;
        }
        __syncthreads();                              // Vt free for next stage
    }

    // ---- block combine across 8 half-waves (smem reused: Sall/llds)
    if (j == 0) llds[hw * NH + h] = l;
    #pragma unroll
    for (int t = 0; t < 4; ++t) {
        float4 s4;
        s4.x = S[4 * t]; s4.y = S[4 * t + 1]; s4.z = S[4 * t + 2]; s4.w = S[4 * t + 3];
        *reinterpret_cast<float4*>(&Sall[hw][h][16 * j + 4 * t]) = s4;
    }
    __syncthreads();
    float* pb = part + (size_t)(b * NSLICE + slice) * PSTRIDE;
    if (tid < 4) {
        float L = 0.f;
        #pragma unroll
        for (int ww = 0; ww < 8; ++ww) L += llds[ww * NH + tid];
        pb[4 + tid] = L;
    }
    #pragma unroll
    for (int r2 = 0; r2 < 2; ++r2) {
        const int e = tid + r2 * 256;
        const int hh = e >> 7, k = e & 127;
        float s = 0.f;
        #pragma unroll
        for (int ww = 0; ww < 8; ++ww) s += Sall[ww][hh][k];
        pb[8 + e] = s;
    }
}

// ---------------- k2: block (b, h): merge NSLICE partials for head h, then
// out[b, h*128+d] = (S[h]/L[h]) . W[:, h*128+d] + bias[h*128+d]
__global__ __launch_bounds__(128) void k2_out(const float* __restrict__ part,
                                              const float* __restrict__ W,
                                              const float* __restrict__ bias,
                                              float* __restrict__ out)
{
    const int b = blockIdx.x;
    const int h = blockIdx.y;
    const int tid = threadIdx.x;     // 0..127
    const float* pb = part + (size_t)b * NSLICE * PSTRIDE;

    __shared__ float Sn[NC];
    __shared__ float sL;
    if (tid == 0) {
        float L = 0.f;
        #pragma unroll
        for (int c = 0; c < NSLICE; ++c) L += pb[(size_t)c * PSTRIDE + 4 + h];
        sL = L;
    }
    __syncthreads();
    {
        float s = 0.f;
        #pragma unroll 4
        for (int c = 0; c < NSLICE; ++c)
            s += pb[(size_t)c * PSTRIDE + 8 + h * NC + tid];
        Sn[tid] = s / sL;
    }
    __syncthreads();
    const int d = h * NC + tid;
    float acc = 0.f;
    #pragma unroll 4
    for (int k = 0; k < NC; ++k) acc += Sn[k] * W[(size_t)k * HC + d];
    out[(size_t)b * HC + d] = acc + bias[d];
}

extern "C" void kernel_launch(void* const* d_in, const int* in_sizes, int n_in,
                              void* d_out, int out_size, void* d_ws, size_t ws_size,
                              hipStream_t stream)
{
    const float* V    = (const float*)d_in[0];
    const int*   gsz  = (const int*)d_in[1];
    const float* W    = (const float*)d_in[2];
    const float* bias = (const float*)d_in[3];
    const float* tune = (const float*)d_in[4];
    float* out  = (float*)d_out;
    float* wtbt = (float*)d_ws;            // 520 floats (516 used)
    float* part = wtbt + PSTRIDE;          // NB*NSLICE*PSTRIDE floats (~2.1 MB)

    hipLaunchKernelGGL(k0_wt, dim3(NC + 1), dim3(128), 0, stream, W, bias, tune, wtbt);
    hipLaunchKernelGGL(k1_part, dim3(NSLICE, NB), dim3(256), 0, stream, V, gsz, wtbt, part);
    hipLaunchKernelGGL(k2_out, dim3(NB, NH), dim3(128), 0, stream, part, W, bias, out);
}